// Round 2
// baseline (34805.341 us; speedup 1.0000x reference)
//
#include <hip/hip_runtime.h>

#define BB 64
#define NN 1000
#define FF 12
#define EE 64
#define HH 128
#define OO 16

__device__ __forceinline__ float rcp_(float x){ return __builtin_amdgcn_rcpf(x); }
__device__ __forceinline__ float sigm_(float x){ return rcp_(1.0f + __expf(-x)); }
// exact algebraic tanh: 1 - 2/(e^{2x}+1)
__device__ __forceinline__ float tanh_(float x){ return 1.0f - 2.0f*rcp_(__expf(2.0f*x) + 1.0f); }

// sum with lane (l - N) within 16-lane DPP row, 0-filled at row edge
template<int CTRL>
__device__ __forceinline__ float dppadd_(float v){
    int s = __builtin_amdgcn_update_dpp(0, __float_as_int(v), CTRL, 0xF, 0xF, true);
    return v + __int_as_float(s);
}

__global__ __launch_bounds__(128, 1)
void decoder_kernel(const float* __restrict__ enc,   // (B,1,N,E)
                    const float* __restrict__ mean,  // (B,FUT,N,O)
                    const float* __restrict__ sv,    // (1,O)
                    const float* __restrict__ h0,    // (2,O)
                    const float* __restrict__ c0,    // (2,H)
                    const float* __restrict__ Wih0,  // (G, E+O)
                    const float* __restrict__ Whh0,  // (G, O)
                    const float* __restrict__ bih0,  // (G)
                    const float* __restrict__ bhh0,  // (G)
                    const float* __restrict__ Whr0,  // (O, H)
                    const float* __restrict__ Wih1,  // (G, O)
                    const float* __restrict__ Whh1,  // (G, O)
                    const float* __restrict__ bih1,  // (G)
                    const float* __restrict__ bhh1,  // (G)
                    const float* __restrict__ Whr1,  // (O, H)
                    float* __restrict__ out)         // (B,FUT,N,O)
{
    const int t  = threadIdx.x;       // 0..127 : cell index k (both layers)
    const int b  = blockIdx.x;
    const int k  = t;
    const int w  = t >> 6;            // wave id (0,1) — owns cells 64w..64w+63
    const int l  = t & 63;
    const int pj = l >> 2;            // projection output j (0..15)
    const int pc4= l & 3;             // projection k-quarter within wave

    __shared__ __align__(16) float s_pp1[2][2][16];  // [pingpong][wave][j] h1 partials
    __shared__ __align__(16) float s_pp2[2][2][16];  // h2 partials
    __shared__ __align__(16) float s_hf[128];        // h_full, swizzled
    __shared__ __align__(16) float s_encN[64];       // enc(node), single-buffer
    __shared__ __align__(16) float s_nm[16];         // node_mean(current node)
    __shared__ __align__(16) float s_nmN[16];        // node_mean(next node)
    __shared__ __align__(16) float s_sv[16];

    // ---- recurrent weights in registers (static-indexed only) ----
    float wl0[64], wh0[64], wi1[64], wh1[64];   // [tau*16 + j]
    float bias1r[4], pre0r[4];
    #pragma unroll
    for (int tau=0; tau<4; ++tau){
        const int g = tau*128 + k;
        const float4* pL = (const float4*)(Wih0 + (size_t)g*(EE+OO) + EE);
        const float4* pH = (const float4*)(Whh0 + (size_t)g*OO);
        const float4* pI = (const float4*)(Wih1 + (size_t)g*OO);
        const float4* pG = (const float4*)(Whh1 + (size_t)g*OO);
        #pragma unroll
        for (int i=0;i<4;i++){
            float4 v;
            v = pL[i]; wl0[tau*16+4*i+0]=v.x; wl0[tau*16+4*i+1]=v.y; wl0[tau*16+4*i+2]=v.z; wl0[tau*16+4*i+3]=v.w;
            v = pH[i]; wh0[tau*16+4*i+0]=v.x; wh0[tau*16+4*i+1]=v.y; wh0[tau*16+4*i+2]=v.z; wh0[tau*16+4*i+3]=v.w;
            v = pI[i]; wi1[tau*16+4*i+0]=v.x; wi1[tau*16+4*i+1]=v.y; wi1[tau*16+4*i+2]=v.z; wi1[tau*16+4*i+3]=v.w;
            v = pG[i]; wh1[tau*16+4*i+0]=v.x; wh1[tau*16+4*i+1]=v.y; wh1[tau*16+4*i+2]=v.z; wh1[tau*16+4*i+3]=v.w;
        }
        bias1r[tau] = bih1[g] + bhh1[g];
        pre0r[tau]  = 0.f;
    }
    // projection weights for this lane's 16-cell slice
    float wq0[16], wq1[16];
    #pragma unroll
    for (int i=0;i<4;i++){
        float4 v0 = *(const float4*)(Whr0 + (size_t)pj*HH + w*64 + pc4*16 + 4*i);
        float4 v1 = *(const float4*)(Whr1 + (size_t)pj*HH + w*64 + pc4*16 + 4*i);
        wq0[4*i+0]=v0.x; wq0[4*i+1]=v0.y; wq0[4*i+2]=v0.z; wq0[4*i+3]=v0.w;
        wq1[4*i+0]=v1.x; wq1[4*i+1]=v1.y; wq1[4*i+2]=v1.z; wq1[4*i+3]=v1.w;
    }

    float c1v = c0[k];
    float c2v = c0[HH + k];

    const float* encB  = enc  + (size_t)b * NN * EE;
    const float* meanB = mean + (size_t)b * FF * NN * OO;
    float*       outB  = out  + (size_t)b * FF * NN * OO;

    // ---- prologue ----
    if (t < 16){
        s_pp1[0][0][t] = h0[t];      s_pp1[0][1][t] = 0.f;
        s_pp2[0][0][t] = h0[OO + t]; s_pp2[0][1][t] = 0.f;
        s_sv[t] = sv[t];
        ((float4*)s_encN)[t] = ((const float4*)encB)[t];     // enc node 0
    } else if (t < 32){
        const int j = t - 16;
        float a = 0.f;
        #pragma unroll
        for (int ff=0; ff<FF; ++ff) a += meanB[((size_t)ff*NN)*OO + j];
        float v = a * (1.0f/12.0f);
        s_nm[j] = v; s_nmN[j] = v;                           // nm node 0
    }
    __syncthreads();

    float4 ef = make_float4(0.f,0.f,0.f,0.f);   // enc prefetch (threads 0..15)
    float  nmr[12];                              // nm prefetch (threads 16..31)
    #pragma unroll
    for (int i=0;i<12;i++) nmr[i]=0.f;

    int step = 0;
    #pragma unroll 1
    for (int n = 0; n < NN; ++n){
        #pragma unroll 1
        for (int f = 0; f < FF; ++f, ++step){
            const int rp = step & 1;

            // ================= PHASE A : layer 0 =================
            // combine projection partials from previous step
            float h1v[16], h2v[16], lv[16];
            {
                const float4* pa = (const float4*)&s_pp1[rp][0][0];
                const float4* pb = (const float4*)&s_pp1[rp][1][0];
                const float4* qa = (const float4*)&s_pp2[rp][0][0];
                const float4* qb = (const float4*)&s_pp2[rp][1][0];
                #pragma unroll
                for (int i=0;i<4;i++){
                    float4 a = pa[i], c = pb[i];
                    h1v[4*i+0]=a.x+c.x; h1v[4*i+1]=a.y+c.y; h1v[4*i+2]=a.z+c.z; h1v[4*i+3]=a.w+c.w;
                    float4 d = qa[i], e = qb[i];
                    h2v[4*i+0]=d.x+e.x; h2v[4*i+1]=d.y+e.y; h2v[4*i+2]=d.z+e.z; h2v[4*i+3]=d.w+e.w;
                }
                const float* nms = (f==0) ? s_nmN : s_nm;
                const float4* nm4 = (const float4*)nms;
                #pragma unroll
                for (int i=0;i<4;i++){
                    float4 m = nm4[i];
                    lv[4*i+0]=h2v[4*i+0]+m.x; lv[4*i+1]=h2v[4*i+1]+m.y;
                    lv[4*i+2]=h2v[4*i+2]+m.z; lv[4*i+3]=h2v[4*i+3]+m.w;
                }
                if (step == 0){
                    const float4* sv4 = (const float4*)s_sv;
                    #pragma unroll
                    for (int i=0;i<4;i++){
                        float4 s0 = sv4[i]; float4 m = nm4[i];
                        lv[4*i+0]=s0.x+m.x; lv[4*i+1]=s0.y+m.y; lv[4*i+2]=s0.z+m.z; lv[4*i+3]=s0.w+m.w;
                    }
                }
            }

            // deferred output for step t-1 (must read s_nm BEFORE the f==0 copy below)
            if (step > 0 && t < OO){
                const int fp = (f==0) ? (FF-1) : (f-1);
                const int np = (f==0) ? (n-1)  : n;
                float val = s_pp2[rp][0][t] + s_pp2[rp][1][t] + s_nm[t];
                outB[((size_t)fp*NN + np)*OO + t] = val;
            }

            if (f == 0){
                if (t < OO) s_nm[t] = s_nmN[t];   // same-thread ordered after out-read
                // per-node constant: bias + enc-dot (weights streamed from L2)
                const float4* ep = (const float4*)s_encN;
                #pragma unroll
                for (int tau=0; tau<4; ++tau){
                    const int g = tau*128 + k;
                    const float4* wp = (const float4*)(Wih0 + (size_t)g*(EE+OO));
                    float s = bih0[g] + bhh0[g];
                    #pragma unroll
                    for (int e=0;e<16;e++){
                        float4 wv = wp[e], evv = ep[e];
                        s += evv.x*wv.x + evv.y*wv.y + evv.z*wv.z + evv.w*wv.w;
                    }
                    pre0r[tau] = s;
                }
            }

            // gates 0 (all 4 gates of cell k, weights in registers)
            float a0=pre0r[0], a1=pre0r[1], a2=pre0r[2], a3=pre0r[3];
            #pragma unroll
            for (int j=0;j<16;j++){
                float xl = lv[j], xh = h1v[j];
                a0 += xl*wl0[j];     a0 += xh*wh0[j];
                a1 += xl*wl0[16+j]; a1 += xh*wh0[16+j];
                a2 += xl*wl0[32+j]; a2 += xh*wh0[32+j];
                a3 += xl*wl0[48+j]; a3 += xh*wh0[48+j];
            }
            // cell 0 — fully thread-local
            {
                float iv=sigm_(a0), fv=sigm_(a1), gv=tanh_(a2), ov=sigm_(a3);
                c1v = fv*c1v + iv*gv;
                float hf = ov * tanh_(c1v);
                s_hf[((k>>4)<<2) + (((k>>2)&3)<<5) + (k&3)] = hf;
            }
            asm volatile("s_waitcnt lgkmcnt(0)" ::: "memory");
            // wave-local projection 0 (reads only own wave's 64 cells)
            {
                float pr = 0.f;
                #pragma unroll
                for (int i=0;i<4;i++){
                    float4 h4 = *(const float4*)&s_hf[(4*w + pc4)*4 + 32*i];
                    pr += h4.x*wq0[4*i+0] + h4.y*wq0[4*i+1] + h4.z*wq0[4*i+2] + h4.w*wq0[4*i+3];
                }
                pr = dppadd_<0x111>(pr);   // + lane-1
                pr = dppadd_<0x112>(pr);   // + lane-2
                if (pc4 == 3) s_pp1[rp^1][w][pj] = pr;
            }
            __syncthreads();   // B1

            // ================= PHASE C : layer 1 =================
            float h1n[16];
            {
                const float4* na = (const float4*)&s_pp1[rp^1][0][0];
                const float4* nb = (const float4*)&s_pp1[rp^1][1][0];
                #pragma unroll
                for (int i=0;i<4;i++){
                    float4 a = na[i], c = nb[i];
                    h1n[4*i+0]=a.x+c.x; h1n[4*i+1]=a.y+c.y; h1n[4*i+2]=a.z+c.z; h1n[4*i+3]=a.w+c.w;
                }
            }

            // prefetch node n+1 (issue early, land 2 phases later)
            if (f == 8 && n+1 < NN){
                if (t < 16){
                    ef = ((const float4*)(encB + (size_t)(n+1)*EE))[t];
                } else if (t < 32){
                    const int j = t - 16;
                    #pragma unroll
                    for (int ff=0; ff<FF; ++ff)
                        nmr[ff] = meanB[((size_t)ff*NN + (n+1))*OO + j];
                }
            }
            if (f == 10 && n+1 < NN){
                if (t < 16){
                    ((float4*)s_encN)[t] = ef;
                } else if (t < 32){
                    float a = 0.f;
                    #pragma unroll
                    for (int ff=0; ff<FF; ++ff) a += nmr[ff];
                    s_nmN[t-16] = a * (1.0f/12.0f);
                }
            }

            // gates 1
            float b0=bias1r[0], b1=bias1r[1], b2=bias1r[2], b3=bias1r[3];
            #pragma unroll
            for (int j=0;j<16;j++){
                float x1 = h1n[j], x2 = h2v[j];
                b0 += x1*wi1[j];     b0 += x2*wh1[j];
                b1 += x1*wi1[16+j]; b1 += x2*wh1[16+j];
                b2 += x1*wi1[32+j]; b2 += x2*wh1[32+j];
                b3 += x1*wi1[48+j]; b3 += x2*wh1[48+j];
            }
            // cell 1
            {
                float iv=sigm_(b0), fv=sigm_(b1), gv=tanh_(b2), ov=sigm_(b3);
                c2v = fv*c2v + iv*gv;
                float hf = ov * tanh_(c2v);
                s_hf[((k>>4)<<2) + (((k>>2)&3)<<5) + (k&3)] = hf;
            }
            asm volatile("s_waitcnt lgkmcnt(0)" ::: "memory");
            // wave-local projection 1
            {
                float pr = 0.f;
                #pragma unroll
                for (int i=0;i<4;i++){
                    float4 h4 = *(const float4*)&s_hf[(4*w + pc4)*4 + 32*i];
                    pr += h4.x*wq1[4*i+0] + h4.y*wq1[4*i+1] + h4.z*wq1[4*i+2] + h4.w*wq1[4*i+3];
                }
                pr = dppadd_<0x111>(pr);
                pr = dppadd_<0x112>(pr);
                if (pc4 == 3) s_pp2[rp^1][w][pj] = pr;
            }
            __syncthreads();   // B2
        }
    }

    // epilogue: output for final step (n=NN-1, f=FF-1); last write went to slot 0
    if (t < OO){
        float val = s_pp2[0][0][t] + s_pp2[0][1][t] + s_nm[t];
        outB[((size_t)(FF-1)*NN + (NN-1))*OO + t] = val;
    }
}

extern "C" void kernel_launch(void* const* d_in, const int* in_sizes, int n_in,
                              void* d_out, int out_size, void* d_ws, size_t ws_size,
                              hipStream_t stream) {
    const float* enc  = (const float*)d_in[0];
    const float* mean = (const float*)d_in[1];
    const float* sv   = (const float*)d_in[2];
    const float* h0   = (const float*)d_in[3];
    const float* c0   = (const float*)d_in[4];
    const float* Wih0 = (const float*)d_in[5];
    const float* Whh0 = (const float*)d_in[6];
    const float* bih0 = (const float*)d_in[7];
    const float* bhh0 = (const float*)d_in[8];
    const float* Whr0 = (const float*)d_in[9];
    const float* Wih1 = (const float*)d_in[10];
    const float* Whh1 = (const float*)d_in[11];
    const float* bih1 = (const float*)d_in[12];
    const float* bhh1 = (const float*)d_in[13];
    const float* Whr1 = (const float*)d_in[14];
    float* out = (float*)d_out;

    decoder_kernel<<<dim3(BB), dim3(128), 0, stream>>>(
        enc, mean, sv, h0, c0,
        Wih0, Whh0, bih0, bhh0, Whr0,
        Wih1, Whh1, bih1, bhh1, Whr1,
        out);
}

// Round 3
// 16168.541 us; speedup vs baseline: 2.1527x; 2.1527x over previous
//
#include <hip/hip_runtime.h>

#define BB 64
#define NN 1000
#define FF 12
#define EE 64
#define HH 128
#define OO 16

__device__ __forceinline__ float rcp_(float x){ return __builtin_amdgcn_rcpf(x); }
// tanh(x) = 1 - 2/(e^{2x}+1)
__device__ __forceinline__ float tanh_(float x){ return 1.0f - 2.0f*rcp_(__expf(2.0f*x) + 1.0f); }

// quad_perm DPP: 0xB1 = xor1 [1,0,3,2], 0x4E = xor2 [2,3,0,1]
template<int CTRL>
__device__ __forceinline__ float qswz_(float x){
    int r = __builtin_amdgcn_update_dpp(0, __float_as_int(x), CTRL, 0xF, 0xF, true);
    return __int_as_float(r);
}
__device__ __forceinline__ float bperm_(int byteIdx, float v){
    return __int_as_float(__builtin_amdgcn_ds_bpermute(byteIdx, __float_as_int(v)));
}
// barrier that drains only LDS (lgkm), NOT vmcnt — out-stores/prefetch stay in flight
__device__ __forceinline__ void barrier_lds_(){
    asm volatile("s_waitcnt lgkmcnt(0)" ::: "memory");
    __builtin_amdgcn_s_barrier();
    asm volatile("" ::: "memory");
}

__global__ __launch_bounds__(512, 2)
void decoder_kernel(const float* __restrict__ enc,   // (B,1,N,E)
                    const float* __restrict__ mean,  // (B,FUT,N,O)
                    const float* __restrict__ sv,    // (1,O)
                    const float* __restrict__ h0,    // (2,O)
                    const float* __restrict__ c0,    // (2,H)
                    const float* __restrict__ Wih0,  // (G, E+O)
                    const float* __restrict__ Whh0,  // (G, O)
                    const float* __restrict__ bih0,  // (G)
                    const float* __restrict__ bhh0,  // (G)
                    const float* __restrict__ Whr0,  // (O, H)
                    const float* __restrict__ Wih1,  // (G, O)
                    const float* __restrict__ Whh1,  // (G, O)
                    const float* __restrict__ bih1,  // (G)
                    const float* __restrict__ bhh1,  // (G)
                    const float* __restrict__ Whr1,  // (O, H)
                    float* __restrict__ out)         // (B,FUT,N,O)
{
    const int t   = threadIdx.x;     // 512 threads
    const int b   = blockIdx.x;
    const int l   = t & 63;          // lane in wave
    const int w   = t >> 6;          // wave 0..7 — owns cells [16w,16w+16)
    const int k   = t >> 2;          // cell 0..127
    const int tau = t & 3;           // 0=i 1=f 2=g 3=o (quad-local)
    const int g   = tau*HH + k;      // gate row (both layers)
    const int pj  = l >> 2;          // projection output j
    const int pc  = l & 3;           // projection chunk (4 cells each)

    __shared__ __align__(16) float s_h1a[2][OO];   // ping-pong h1 accumulators
    __shared__ __align__(16) float s_h2a[2][OO];   // ping-pong h2 accumulators
    __shared__ __align__(16) float s_nm[2][OO];    // node_mean, slot n&1
    __shared__ __align__(16) float s_enc[EE];      // enc(node), single buffer

    // ---- per-thread weights (64 + 8 regs, static-indexed) ----
    float wl0[16], wh0[16], wi1[16], wh1[16], wq0[4], wq1[4];
    {
        const float4* pL = (const float4*)(Wih0 + (size_t)g*(EE+OO) + EE);
        const float4* pH = (const float4*)(Whh0 + (size_t)g*OO);
        const float4* pI = (const float4*)(Wih1 + (size_t)g*OO);
        const float4* pG = (const float4*)(Whh1 + (size_t)g*OO);
        #pragma unroll
        for (int i=0;i<4;i++){
            float4 v;
            v=pL[i]; wl0[4*i]=v.x; wl0[4*i+1]=v.y; wl0[4*i+2]=v.z; wl0[4*i+3]=v.w;
            v=pH[i]; wh0[4*i]=v.x; wh0[4*i+1]=v.y; wh0[4*i+2]=v.z; wh0[4*i+3]=v.w;
            v=pI[i]; wi1[4*i]=v.x; wi1[4*i+1]=v.y; wi1[4*i+2]=v.z; wi1[4*i+3]=v.w;
            v=pG[i]; wh1[4*i]=v.x; wh1[4*i+1]=v.y; wh1[4*i+2]=v.z; wh1[4*i+3]=v.w;
        }
        float4 q0 = *(const float4*)(Whr0 + (size_t)pj*HH + w*16 + pc*4);
        float4 q1 = *(const float4*)(Whr1 + (size_t)pj*HH + w*16 + pc*4);
        wq0[0]=q0.x; wq0[1]=q0.y; wq0[2]=q0.z; wq0[3]=q0.w;
        wq1[0]=q1.x; wq1[1]=q1.y; wq1[2]=q1.z; wq1[3]=q1.w;
    }
    const float bias0r = bih0[g] + bhh0[g];
    const float bias1r = bih1[g] + bhh1[g];
    // step-0 correction: gates1 uses h2a seeded with sv, true h2_0 = h0[1]
    float corr1 = 0.f;
    #pragma unroll
    for (int i=0;i<4;i++){
        float4 hv  = *(const float4*)(h0 + OO + 4*i);
        float4 svv = *(const float4*)(sv + 4*i);
        corr1 += (hv.x-svv.x)*wh1[4*i]   + (hv.y-svv.y)*wh1[4*i+1]
               + (hv.z-svv.z)*wh1[4*i+2] + (hv.w-svv.w)*wh1[4*i+3];
    }
    // branch-free activation constant: act = 1 - am*rcp(exp(am*x)+1)
    const float am = (tau==2) ? 2.0f : 1.0f;

    float c1v = c0[k];          // meaningful in lane tau==1 of each quad
    float c2v = c0[HH+k];

    const float* encB  = enc  + (size_t)b * NN * EE;
    const float* meanB = mean + (size_t)b * FF * NN * OO;
    float*       outB  = out  + (size_t)b * FF * NN * OO;

    // ---- prologue ----
    if (t < OO){
        s_h1a[0][t] = h0[t];
        s_h1a[1][t] = 0.f;
        s_h2a[0][t] = sv[t];          // 'last' seed (corr1 fixes gates1)
        s_h2a[1][t] = 0.f;
        ((float4*)s_enc)[t] = ((const float4*)encB)[t];
    } else if (t < 2*OO){
        const int j = t - OO;
        float a = 0.f;
        #pragma unroll
        for (int ff=0; ff<FF; ++ff) a += meanB[((size_t)ff*NN)*OO + j];
        s_nm[0][j] = a * (1.0f/12.0f);
    }
    __syncthreads();

    float4 ef = make_float4(0.f,0.f,0.f,0.f);
    float nmr[12];
    #pragma unroll
    for (int i=0;i<12;i++) nmr[i]=0.f;
    float pre0 = 0.f;

    int step = 0;
    #pragma unroll 1
    for (int n = 0; n < NN; ++n){
        #pragma unroll 1
        for (int f = 0; f < FF; ++f, ++step){
            const int rp = step & 1;

            // ================= PHASE A : layer 0 =================
            float h1v[16], h2v[16];
            {
                const float4* pa = (const float4*)s_h1a[rp];
                const float4* pb = (const float4*)s_h2a[rp];
                #pragma unroll
                for (int i=0;i<4;i++){
                    float4 a = pa[i]; h1v[4*i]=a.x; h1v[4*i+1]=a.y; h1v[4*i+2]=a.z; h1v[4*i+3]=a.w;
                    float4 c = pb[i]; h2v[4*i]=c.x; h2v[4*i+1]=c.y; h2v[4*i+2]=c.z; h2v[4*i+3]=c.w;
                }
            }
            // deferred output write for step t-1
            if (step > 0 && t < OO){
                const int fp = (f==0) ? (FF-1) : (f-1);
                const int np = (f==0) ? (n-1)  : n;
                const int sl = (f==0) ? ((n&1)^1) : (n&1);
                outB[((size_t)fp*NN + np)*OO + t] = s_h2a[rp][t] + s_nm[sl][t];
            }
            if (t < OO) s_h2a[rp^1][t] = 0.f;      // zero phase-B add target

            if (f == 0){
                // per-node constant: bias + enc·W + nm·W_loop (weights from L2)
                float s = bias0r;
                const float4* wp = (const float4*)(Wih0 + (size_t)g*(EE+OO));
                const float4* ep = (const float4*)s_enc;
                #pragma unroll
                for (int e=0;e<16;e++){
                    float4 wv = wp[e], evv = ep[e];
                    s += evv.x*wv.x + evv.y*wv.y + evv.z*wv.z + evv.w*wv.w;
                }
                const float4* nm4 = (const float4*)s_nm[n&1];
                #pragma unroll
                for (int i=0;i<4;i++){
                    float4 m = nm4[i];
                    s += m.x*wl0[4*i] + m.y*wl0[4*i+1] + m.z*wl0[4*i+2] + m.w*wl0[4*i+3];
                }
                pre0 = s;
            }

            // gates0: K=16+16, weights in regs, inputs broadcast
            float aL=0.f, aH=0.f;
            #pragma unroll
            for (int j=0;j<16;j++){ aL += h2v[j]*wl0[j]; aH += h1v[j]*wh0[j]; }
            float x0  = pre0 + aL + aH;
            float act = 1.f - am * rcp_(__expf(am*x0) + 1.f);   // sigm or tanh

            // cell0: quad-DPP dance (lanes tau: 0=i 1=f 2=g 3=o)
            float r2 = qswz_<0x4E>(act);            // xor2
            float P  = act * r2;                    // lane0: sigm(i)*tanh(g)
            float s2 = (tau==1) ? act*c1v : P;      // lane1: sigm(f)*c
            float cn = s2 + qswz_<0xB1>(s2);        // lanes0,1: new c
            c1v = cn;
            float tc = tanh_(cn);
            float hf = act * qswz_<0x4E>(tc);       // lane3: sigm(o)*tanh(c')

            // proj0: gather hf from lanes 4m+3 via bpermute, quad-reduce, atomic
            {
                const int bb = pc*64 + 12;          // byte idx of lane 16*pc+3
                float v0 = bperm_(bb,    hf);
                float v1 = bperm_(bb+16, hf);
                float v2 = bperm_(bb+32, hf);
                float v3 = bperm_(bb+48, hf);
                float pr = v0*wq0[0] + v1*wq0[1] + v2*wq0[2] + v3*wq0[3];
                pr += qswz_<0xB1>(pr);
                pr += qswz_<0x4E>(pr);
                if (pc == 0) atomicAdd(&s_h1a[rp^1][pj], pr);
            }
            barrier_lds_();                          // B1

            // ================= PHASE B : layer 1 =================
            float h1n[16];
            {
                const float4* na = (const float4*)s_h1a[rp^1];
                #pragma unroll
                for (int i=0;i<4;i++){
                    float4 a = na[i]; h1n[4*i]=a.x; h1n[4*i+1]=a.y; h1n[4*i+2]=a.z; h1n[4*i+3]=a.w;
                }
            }
            if (t < OO) s_h1a[rp][t] = 0.f;          // zero next phase-A add target

            // prefetch node n+1 (issue f==8, land f==10; no vmcnt drain at barriers)
            if (f == 8 && n+1 < NN){
                if (t < OO){
                    ef = ((const float4*)(encB + (size_t)(n+1)*EE))[t];
                } else if (t < 2*OO){
                    const int j = t - OO;
                    #pragma unroll
                    for (int ff=0; ff<FF; ++ff) nmr[ff] = meanB[((size_t)ff*NN + (n+1))*OO + j];
                }
            }
            if (f == 10 && n+1 < NN){
                if (t < OO){
                    ((float4*)s_enc)[t] = ef;
                } else if (t < 2*OO){
                    float a = 0.f;
                    #pragma unroll
                    for (int ff=0; ff<FF; ++ff) a += nmr[ff];
                    s_nm[(n+1)&1][t-OO] = a * (1.0f/12.0f);
                }
            }

            // gates1
            float aI=0.f, aH2=0.f;
            #pragma unroll
            for (int j=0;j<16;j++){ aI += h1n[j]*wi1[j]; aH2 += h2v[j]*wh1[j]; }
            float x1 = bias1r + aI + aH2;
            if (step == 0) x1 += corr1;
            float act1 = 1.f - am * rcp_(__expf(am*x1) + 1.f);

            // cell1
            float r2b = qswz_<0x4E>(act1);
            float Pb  = act1 * r2b;
            float s2b = (tau==1) ? act1*c2v : Pb;
            float cnb = s2b + qswz_<0xB1>(s2b);
            c2v = cnb;
            float tcb = tanh_(cnb);
            float hf2 = act1 * qswz_<0x4E>(tcb);

            // proj1
            {
                const int bb = pc*64 + 12;
                float v0 = bperm_(bb,    hf2);
                float v1 = bperm_(bb+16, hf2);
                float v2 = bperm_(bb+32, hf2);
                float v3 = bperm_(bb+48, hf2);
                float pr = v0*wq1[0] + v1*wq1[1] + v2*wq1[2] + v3*wq1[3];
                pr += qswz_<0xB1>(pr);
                pr += qswz_<0x4E>(pr);
                if (pc == 0) atomicAdd(&s_h2a[rp^1][pj], pr);
            }
            barrier_lds_();                          // B2
        }
    }

    // epilogue: final step (n=NN-1,f=FF-1) landed in s_h2a[0]
    if (t < OO)
        outB[((size_t)(FF-1)*NN + (NN-1))*OO + t] = s_h2a[0][t] + s_nm[(NN-1)&1][t];
}

extern "C" void kernel_launch(void* const* d_in, const int* in_sizes, int n_in,
                              void* d_out, int out_size, void* d_ws, size_t ws_size,
                              hipStream_t stream) {
    const float* enc  = (const float*)d_in[0];
    const float* mean = (const float*)d_in[1];
    const float* sv   = (const float*)d_in[2];
    const float* h0   = (const float*)d_in[3];
    const float* c0   = (const float*)d_in[4];
    const float* Wih0 = (const float*)d_in[5];
    const float* Whh0 = (const float*)d_in[6];
    const float* bih0 = (const float*)d_in[7];
    const float* bhh0 = (const float*)d_in[8];
    const float* Whr0 = (const float*)d_in[9];
    const float* Wih1 = (const float*)d_in[10];
    const float* Whh1 = (const float*)d_in[11];
    const float* bih1 = (const float*)d_in[12];
    const float* bhh1 = (const float*)d_in[13];
    const float* Whr1 = (const float*)d_in[14];
    float* out = (float*)d_out;

    decoder_kernel<<<dim3(BB), dim3(512), 0, stream>>>(
        enc, mean, sv, h0, c0,
        Wih0, Whh0, bih0, bhh0, Whr0,
        Wih1, Whh1, bih1, bhh1, Whr1,
        out);
}